// Round 7
// baseline (641.543 us; speedup 1.0000x reference)
//
#include <hip/hip_runtime.h>
#include <stdint.h>

#define DEV __device__ __forceinline__

typedef __bf16 bf16x8 __attribute__((ext_vector_type(8)));
typedef float  f32x4  __attribute__((ext_vector_type(4)));

DEV unsigned short f2bf(float f) {
    union { float f; unsigned int u; } v; v.f = f;
    unsigned int u = v.u;
    unsigned int r = u + 0x7FFFu + ((u >> 16) & 1u);   // RNE
    return (unsigned short)(r >> 16);
}

DEV f32x4 mfma16(bf16x8 a, bf16x8 b, f32x4 c) {
    return __builtin_amdgcn_mfma_f32_16x16x32_bf16(a, b, c, 0, 0, 0);
}

// async global->LDS, 16B per lane; LDS dest = wave-uniform base + lane*16
DEV void gll16(const unsigned short* g, unsigned short* l) {
    __builtin_amdgcn_global_load_lds(
        (const __attribute__((address_space(1))) unsigned int*)g,
        (__attribute__((address_space(3))) unsigned int*)l, 16, 0, 0);
}

// ---------------------------------------------------------------- convert
__global__ __launch_bounds__(256)
void k_f32_to_bf16(const float* __restrict__ in, unsigned short* __restrict__ out, int n) {
    int i = (blockIdx.x * 256 + threadIdx.x) * 4;
    if (i + 3 < n) {
        float4 f = *(const float4*)(in + i);
        ushort4 o;
        o.x = f2bf(f.x); o.y = f2bf(f.y); o.z = f2bf(f.z); o.w = f2bf(f.w);
        *(ushort4*)(out + i) = o;
    } else {
        for (; i < n; ++i) out[i] = f2bf(in[i]);
    }
}

// ------------------------------------------------- transpose f32[K][N] -> bf16[N][K]
__global__ __launch_bounds__(256)
void k_transpose_bf16(const float* __restrict__ in, unsigned short* __restrict__ out,
                      int K, int N) {
    __shared__ unsigned short tile[64][65];
    const int nt = blockIdx.x * 64;
    const int kt = blockIdx.y * 64;
    const int tx = threadIdx.x & 63;
    const int ty = threadIdx.x >> 6;   // 0..3
#pragma unroll
    for (int r = 0; r < 16; ++r) {
        int row = ty * 16 + r;
        tile[row][tx] = f2bf(in[(size_t)(kt + row) * N + nt + tx]);
    }
    __syncthreads();
#pragma unroll
    for (int r = 0; r < 16; ++r) {
        int row = ty * 16 + r;
        out[(size_t)(nt + row) * K + kt + tx] = tile[tx][row];
    }
}

// --------------------------- transpose V cols of qkv -> vtb[b][hk][d][T] (bf16)
__global__ __launch_bounds__(256)
void k_transpose_v(const unsigned short* __restrict__ qkv, unsigned short* __restrict__ vtb) {
    const int T = 2048, QKVC = 3072;
    const int bh = blockIdx.z;             // b*4 + hk
    const int t0 = blockIdx.x * 64;
    const int d0 = blockIdx.y * 64;
    __shared__ unsigned short tile[64][65];
    const int tx = threadIdx.x & 63;
    const int ty = threadIdx.x >> 6;
    const unsigned short* src = qkv + (size_t)(bh >> 2) * T * QKVC + 2560 + (bh & 3) * 128;
#pragma unroll
    for (int r = 0; r < 16; ++r) {
        int row = ty * 16 + r;
        tile[row][tx] = src[(size_t)(t0 + row) * QKVC + d0 + tx];
    }
    __syncthreads();
    unsigned short* dst = vtb + ((size_t)bh * 128 + d0) * T + t0;
#pragma unroll
    for (int r = 0; r < 16; ++r) {
        int row = ty * 16 + r;
        dst[(size_t)row * T + tx] = tile[tx][row];
    }
}

// ------------------------------------------------------------------ GEMM (m97-style)
template <bool OUT_BF16>
__global__ __launch_bounds__(256)
void k_gemm_bt(const unsigned short* __restrict__ A,
               const unsigned short* __restrict__ Bt,
               void* __restrict__ Cout,
               const float* __restrict__ bias,
               int M, int N, int K) {
    __shared__ unsigned short ldsA[128 * 32];
    __shared__ unsigned short ldsB[128 * 32];

    const int t    = threadIdx.x;
    const int lane = t & 63;
    const int wave = t >> 6;
    const int wr   = wave >> 1, wc = wave & 1;
    const int r16  = lane & 15, quad = lane >> 4;
    const int rowBase = blockIdx.y * 128;
    const int colBase = blockIdx.x * 128;

    f32x4 acc[4][4];
#pragma unroll
    for (int i = 0; i < 4; ++i)
#pragma unroll
        for (int j = 0; j < 4; ++j) { f32x4 z = {0.f, 0.f, 0.f, 0.f}; acc[i][j] = z; }

    const int lr = lane >> 2;
    const int lc = (lane & 3) * 8;
    const unsigned short* Ag = A  + (size_t)(rowBase + wave * 32 + lr) * K + lc;
    const unsigned short* Bg = Bt + (size_t)(colBase + wave * 32 + lr) * K + lc;
    unsigned short* lA = ldsA + wave * 32 * 32;   // wave-uniform
    unsigned short* lB = ldsB + wave * 32 * 32;

    for (int kt = 0; kt < K; kt += 32) {
        gll16(Ag + kt,                    lA);
        gll16(Ag + (size_t)16 * K + kt,   lA + 512);
        gll16(Bg + kt,                    lB);
        gll16(Bg + (size_t)16 * K + kt,   lB + 512);
        asm volatile("s_waitcnt vmcnt(0)" ::: "memory");
        __syncthreads();

        bf16x8 af[4], bfr[4];
#pragma unroll
        for (int i = 0; i < 4; ++i)
            af[i] = *(const bf16x8*)(ldsA + (wr * 64 + i * 16 + r16) * 32 + quad * 8);
#pragma unroll
        for (int j = 0; j < 4; ++j)
            bfr[j] = *(const bf16x8*)(ldsB + (wc * 64 + j * 16 + r16) * 32 + quad * 8);
#pragma unroll
        for (int i = 0; i < 4; ++i)
#pragma unroll
            for (int j = 0; j < 4; ++j)
                acc[i][j] = mfma16(af[i], bfr[j], acc[i][j]);
        __syncthreads();
    }

    const int orow = rowBase + wr * 64 + quad * 4;
    const int ocol = colBase + wc * 64 + r16;
    if (OUT_BF16) {
        unsigned short* O = (unsigned short*)Cout;
#pragma unroll
        for (int i = 0; i < 4; ++i)
#pragma unroll
            for (int j = 0; j < 4; ++j)
#pragma unroll
                for (int r = 0; r < 4; ++r)
                    O[(size_t)(orow + i * 16 + r) * N + ocol + j * 16] = f2bf(acc[i][j][r]);
    } else {
        float* O = (float*)Cout;
#pragma unroll
        for (int j = 0; j < 4; ++j) {
            float bv = bias ? bias[ocol + j * 16] : 0.f;
#pragma unroll
            for (int i = 0; i < 4; ++i)
#pragma unroll
                for (int r = 0; r < 4; ++r)
                    O[(size_t)(orow + i * 16 + r) * N + ocol + j * 16] = acc[i][j][r] + bv;
        }
    }
}

// ------------------------------------------------------------- attention
// One block = (b, head-PAIR, 64-row q-tile), 512 threads = 8 waves.
// Waves 0-3 process head h0 (16 q rows each), waves 4-7 head h0+1 — the two
// GQA-sibling heads share each staged K/V tile (2x MFMA per staged byte) with
// NO extra per-wave registers (the R5 spill lesson).
// Fixed-max softmax: p = e^{s*scale-10}; exact after final o/l.
// S computed transposed (A=K, B=Q) -> packed b64 P writes, b128 P A-frag reads.
// LDS = K 16K + Vt 16K + P 16K = 48KB -> 3 blocks/CU. VGPR ~64.
__global__ __launch_bounds__(512, 6)
void k_attn(const unsigned short* __restrict__ qkv,  // [B,T,3072] bf16
            const unsigned short* __restrict__ vtb,  // [B,HKV,D,T] bf16
            unsigned short* __restrict__ yb) {       // [B,T,C] bf16
    const int T = 2048, C = 2048, QKVC = 3072;
    const int qt = (int)gridDim.x - 1 - (int)blockIdx.x;   // long blocks first
    const int hk = blockIdx.y >> 1;
    const int h  = hk * 4 + (blockIdx.y & 1) * 2 + (threadIdx.x >> 8);  // wave 0-3: h0, 4-7: h0+1
    const int b  = blockIdx.z;

    const int t = threadIdx.x, lane = t & 63, wave = t >> 6;   // 0..7
    const int wv = wave & 3;                                   // q-row group in tile
    const int r16 = lane & 15, quad = lane >> 4;

    __shared__ unsigned short ldsK[4 * 64 * 32];     // [kk][s][32d]
    __shared__ unsigned short ldsVt[2 * 128 * 32];   // [kk][d][32s]
    __shared__ unsigned short ldsP[8][16 * 64];      // per-wave, s XOR-swizzled

    const int qBase = qt * 64;
    const int swz = (r16 & 7) * 8;

    // Q B-fragments (this wave's head), reused every kv tile
    const size_t qrow = (size_t)b * T + qBase + wv * 16 + r16;
    bf16x8 qf[4];
#pragma unroll
    for (int kk = 0; kk < 4; ++kk)
        qf[kk] = *(const bf16x8*)(qkv + qrow * QKVC + h * 128 + kk * 32 + quad * 8);

    f32x4 o[8];
#pragma unroll
    for (int dj = 0; dj < 8; ++dj) { f32x4 z = {0.f, 0.f, 0.f, 0.f}; o[dj] = z; }
    float lpart = 0.f;

    const float sc_l2e = 0.08838834764831845f * 1.4426950408889634f; // scale*log2(e)
    const float MSUB   = 10.0f * 1.4426950408889634f;                // fixed max (log2)

    const unsigned short* kg = qkv + (size_t)b * T * QKVC + 2048 + hk * 128;
    const unsigned short* vt = vtb + (size_t)(b * 4 + hk) * 128 * T;

    const int lr = lane >> 2;          // 0..15
    const int lc = (lane & 3) * 8;     // 0,8,16,24
    unsigned short* Pw = &ldsP[wave][0];
    const int qloc = wv * 16 + r16;

    for (int kv = 0; kv <= qBase; kv += 64) {
        // ---- async stage across all 8 waves: 16 K-chunks + 16 Vt-chunks of 1KB
        {
            // K chunk c = wave*2+q (c: kk = c>>2, s16 = c&3)
#pragma unroll
            for (int q = 0; q < 2; ++q) {
                int c = wave * 2 + q;
                int kk = c >> 2, s16 = c & 3;
                gll16(kg + (size_t)(kv + s16 * 16 + lr) * QKVC + kk * 32 + lc,
                      ldsK + kk * 2048 + s16 * 512);
                // Vt chunk c: kk2 = c>>3, d16 = c&7
                int kk2 = c >> 3, d16 = c & 7;
                gll16(vt + (size_t)(d16 * 16 + lr) * T + kv + kk2 * 32 + lc,
                      ldsVt + kk2 * 4096 + d16 * 512);
            }
        }
        asm volatile("s_waitcnt vmcnt(0)" ::: "memory");
        __syncthreads();

        // ---- S^T = K Q^T : C-layout q = r16, kv_local = mi*16 + quad*4 + reg
        f32x4 sacc[4];
#pragma unroll
        for (int mi = 0; mi < 4; ++mi) { f32x4 z = {0.f, 0.f, 0.f, 0.f}; sacc[mi] = z; }
#pragma unroll
        for (int mi = 0; mi < 4; ++mi)
#pragma unroll
            for (int kk = 0; kk < 4; ++kk) {
                bf16x8 kf = *(const bf16x8*)(ldsK + kk * 2048 + (mi * 16 + r16) * 32 + quad * 8);
                sacc[mi] = mfma16(kf, qf[kk], sacc[mi]);
            }

        // ---- p = e^{s*scale - 10}, causal mask on diag, packed b64 P write
        const bool diag = (kv == qBase);
#pragma unroll
        for (int mi = 0; mi < 4; ++mi) {
            float pv[4];
#pragma unroll
            for (int i = 0; i < 4; ++i) {
                float p = exp2f(sacc[mi][i] * sc_l2e - MSUB);
                if (diag && (mi * 16 + quad * 4 + i > qloc)) p = 0.f;
                lpart += p;
                pv[i] = p;
            }
            union { ushort4 u4; __bf16 hh[4]; } pk;
            pk.hh[0] = (__bf16)pv[0]; pk.hh[1] = (__bf16)pv[1];
            pk.hh[2] = (__bf16)pv[2]; pk.hh[3] = (__bf16)pv[3];
            *(ushort4*)(Pw + r16 * 64 + ((mi * 16 + quad * 4) ^ swz)) = pk.u4;
        }
        asm volatile("s_waitcnt lgkmcnt(0)" ::: "memory");

        // ---- O += P V  (A=P from swizzled LDS, B=V^T frags)
#pragma unroll
        for (int kk = 0; kk < 2; ++kk) {
            bf16x8 pf = *(const bf16x8*)(Pw + r16 * 64 + ((kk * 32 + quad * 8) ^ swz));
#pragma unroll
            for (int dj = 0; dj < 8; ++dj) {
                bf16x8 vf = *(const bf16x8*)(ldsVt + kk * 4096 + (dj * 16 + r16) * 32 + quad * 8);
                o[dj] = mfma16(pf, vf, o[dj]);
            }
        }
        __syncthreads();
    }

    // ---- final row-sum reduce (q = r16 replicated over quads) + gather + store
    lpart += __shfl_xor(lpart, 16, 64);
    lpart += __shfl_xor(lpart, 32, 64);
#pragma unroll
    for (int i = 0; i < 4; ++i) {
        float inv = 1.0f / __shfl(lpart, quad * 4 + i, 64);
        size_t row = (size_t)b * T + qBase + wv * 16 + quad * 4 + i;
#pragma unroll
        for (int dj = 0; dj < 8; ++dj)
            yb[row * C + h * 128 + dj * 16 + r16] = f2bf(o[dj][i] * inv);
    }
}

// ------------------------------------------------------------------ launch
extern "C" void kernel_launch(void* const* d_in, const int* in_sizes, int n_in,
                              void* d_out, int out_size, void* d_ws, size_t ws_size,
                              hipStream_t stream) {
    (void)in_sizes; (void)n_in; (void)out_size; (void)ws_size;
    const float* x   = (const float*)d_in[0];
    const float* Wq  = (const float*)d_in[1];
    const float* Wkv = (const float*)d_in[2];
    const float* Wc  = (const float*)d_in[3];
    const float* bc  = (const float*)d_in[4];

    const int B = 4, T = 2048, C = 2048;
    const int M = B * T;          // 8192
    const int NKV = 1024;         // 2*HKV*D
    const int NQKV = C + NKV;     // 3072

    char* ws = (char*)d_ws;
    unsigned short* xb    = (unsigned short*)ws; ws += (size_t)M * C * 2;
    unsigned short* WqkvT = (unsigned short*)ws; ws += (size_t)NQKV * C * 2;
    unsigned short* WcT   = (unsigned short*)ws; ws += (size_t)C * C * 2;
    unsigned short* qkv   = (unsigned short*)ws; ws += (size_t)M * NQKV * 2;
    unsigned short* ybuf  = (unsigned short*)ws; ws += (size_t)M * C * 2;
    unsigned short* vtb   = (unsigned short*)ws; ws += (size_t)B * 4 * 128 * T * 2;

    const int nX = M * C;
    k_f32_to_bf16<<<nX / 4 / 256, 256, 0, stream>>>(x, xb, nX);
    // WqkvT[n][k]: rows 0..2047 = Wq^T, rows 2048..3071 = Wkv^T
    k_transpose_bf16<<<dim3(C / 64, C / 64), 256, 0, stream>>>(Wq, WqkvT, C, C);
    k_transpose_bf16<<<dim3(NKV / 64, C / 64), 256, 0, stream>>>(Wkv, WqkvT + (size_t)C * C, C, NKV);
    k_transpose_bf16<<<dim3(C / 64, C / 64), 256, 0, stream>>>(Wc, WcT, C, C);

    // fused q/k/v projection: qkv[M][3072]
    k_gemm_bt<true><<<dim3(NQKV / 128, M / 128), 256, 0, stream>>>(xb, WqkvT, qkv, nullptr, M, NQKV, C);

    k_transpose_v<<<dim3(T / 64, 2, B * 4), 256, 0, stream>>>(qkv, vtb);

    k_attn<<<dim3(T / 64, 8, B), 512, 0, stream>>>(qkv, vtb, ybuf);

    k_gemm_bt<false><<<dim3(C / 128, M / 128), 256, 0, stream>>>(ybuf, WcT, (void*)d_out, bc, M, C, C);
}

// Round 8
// 567.231 us; speedup vs baseline: 1.1310x; 1.1310x over previous
//
#include <hip/hip_runtime.h>
#include <stdint.h>

#define DEV __device__ __forceinline__

typedef __bf16 bf16x8 __attribute__((ext_vector_type(8)));
typedef float  f32x4  __attribute__((ext_vector_type(4)));

DEV unsigned short f2bf(float f) {
    union { float f; unsigned int u; } v; v.f = f;
    unsigned int u = v.u;
    unsigned int r = u + 0x7FFFu + ((u >> 16) & 1u);   // RNE
    return (unsigned short)(r >> 16);
}

DEV f32x4 mfma16(bf16x8 a, bf16x8 b, f32x4 c) {
    return __builtin_amdgcn_mfma_f32_16x16x32_bf16(a, b, c, 0, 0, 0);
}

// async global->LDS, 16B per lane; LDS dest = wave-uniform base + lane*16
DEV void gll16(const unsigned short* g, unsigned short* l) {
    __builtin_amdgcn_global_load_lds(
        (const __attribute__((address_space(1))) unsigned int*)g,
        (__attribute__((address_space(3))) unsigned int*)l, 16, 0, 0);
}

// ---------------------------------------------------------------- convert
__global__ __launch_bounds__(256)
void k_f32_to_bf16(const float* __restrict__ in, unsigned short* __restrict__ out, int n) {
    int i = (blockIdx.x * 256 + threadIdx.x) * 4;
    if (i + 3 < n) {
        float4 f = *(const float4*)(in + i);
        ushort4 o;
        o.x = f2bf(f.x); o.y = f2bf(f.y); o.z = f2bf(f.z); o.w = f2bf(f.w);
        *(ushort4*)(out + i) = o;
    } else {
        for (; i < n; ++i) out[i] = f2bf(in[i]);
    }
}

// ------------------------------------------------- transpose f32[K][N] -> bf16[N][K]
__global__ __launch_bounds__(256)
void k_transpose_bf16(const float* __restrict__ in, unsigned short* __restrict__ out,
                      int K, int N) {
    __shared__ unsigned short tile[64][65];
    const int nt = blockIdx.x * 64;
    const int kt = blockIdx.y * 64;
    const int tx = threadIdx.x & 63;
    const int ty = threadIdx.x >> 6;   // 0..3
#pragma unroll
    for (int r = 0; r < 16; ++r) {
        int row = ty * 16 + r;
        tile[row][tx] = f2bf(in[(size_t)(kt + row) * N + nt + tx]);
    }
    __syncthreads();
#pragma unroll
    for (int r = 0; r < 16; ++r) {
        int row = ty * 16 + r;
        out[(size_t)(nt + row) * K + kt + tx] = tile[tx][row];
    }
}

// --------------------------- transpose V cols of qkv -> vtb[b][hk][d][T] (bf16)
__global__ __launch_bounds__(256)
void k_transpose_v(const unsigned short* __restrict__ qkv, unsigned short* __restrict__ vtb) {
    const int T = 2048, QKVC = 3072;
    const int bh = blockIdx.z;             // b*4 + hk
    const int t0 = blockIdx.x * 64;
    const int d0 = blockIdx.y * 64;
    __shared__ unsigned short tile[64][65];
    const int tx = threadIdx.x & 63;
    const int ty = threadIdx.x >> 6;
    const unsigned short* src = qkv + (size_t)(bh >> 2) * T * QKVC + 2560 + (bh & 3) * 128;
#pragma unroll
    for (int r = 0; r < 16; ++r) {
        int row = ty * 16 + r;
        tile[row][tx] = src[(size_t)(t0 + row) * QKVC + d0 + tx];
    }
    __syncthreads();
    unsigned short* dst = vtb + ((size_t)bh * 128 + d0) * T + t0;
#pragma unroll
    for (int r = 0; r < 16; ++r) {
        int row = ty * 16 + r;
        dst[(size_t)row * T + tx] = tile[tx][row];
    }
}

// ------------------------------------------------------------------ GEMM (m97-style)
template <bool OUT_BF16>
__global__ __launch_bounds__(256)
void k_gemm_bt(const unsigned short* __restrict__ A,
               const unsigned short* __restrict__ Bt,
               void* __restrict__ Cout,
               const float* __restrict__ bias,
               int M, int N, int K) {
    __shared__ unsigned short ldsA[128 * 32];
    __shared__ unsigned short ldsB[128 * 32];

    const int t    = threadIdx.x;
    const int lane = t & 63;
    const int wave = t >> 6;
    const int wr   = wave >> 1, wc = wave & 1;
    const int r16  = lane & 15, quad = lane >> 4;
    const int rowBase = blockIdx.y * 128;
    const int colBase = blockIdx.x * 128;

    f32x4 acc[4][4];
#pragma unroll
    for (int i = 0; i < 4; ++i)
#pragma unroll
        for (int j = 0; j < 4; ++j) { f32x4 z = {0.f, 0.f, 0.f, 0.f}; acc[i][j] = z; }

    const int lr = lane >> 2;
    const int lc = (lane & 3) * 8;
    const unsigned short* Ag = A  + (size_t)(rowBase + wave * 32 + lr) * K + lc;
    const unsigned short* Bg = Bt + (size_t)(colBase + wave * 32 + lr) * K + lc;
    unsigned short* lA = ldsA + wave * 32 * 32;   // wave-uniform
    unsigned short* lB = ldsB + wave * 32 * 32;

    for (int kt = 0; kt < K; kt += 32) {
        gll16(Ag + kt,                    lA);
        gll16(Ag + (size_t)16 * K + kt,   lA + 512);
        gll16(Bg + kt,                    lB);
        gll16(Bg + (size_t)16 * K + kt,   lB + 512);
        asm volatile("s_waitcnt vmcnt(0)" ::: "memory");
        __syncthreads();

        bf16x8 af[4], bfr[4];
#pragma unroll
        for (int i = 0; i < 4; ++i)
            af[i] = *(const bf16x8*)(ldsA + (wr * 64 + i * 16 + r16) * 32 + quad * 8);
#pragma unroll
        for (int j = 0; j < 4; ++j)
            bfr[j] = *(const bf16x8*)(ldsB + (wc * 64 + j * 16 + r16) * 32 + quad * 8);
#pragma unroll
        for (int i = 0; i < 4; ++i)
#pragma unroll
            for (int j = 0; j < 4; ++j)
                acc[i][j] = mfma16(af[i], bfr[j], acc[i][j]);
        __syncthreads();
    }

    const int orow = rowBase + wr * 64 + quad * 4;
    const int ocol = colBase + wc * 64 + r16;
    if (OUT_BF16) {
        unsigned short* O = (unsigned short*)Cout;
#pragma unroll
        for (int i = 0; i < 4; ++i)
#pragma unroll
            for (int j = 0; j < 4; ++j)
#pragma unroll
                for (int r = 0; r < 4; ++r)
                    O[(size_t)(orow + i * 16 + r) * N + ocol + j * 16] = f2bf(acc[i][j][r]);
    } else {
        float* O = (float*)Cout;
#pragma unroll
        for (int j = 0; j < 4; ++j) {
            float bv = bias ? bias[ocol + j * 16] : 0.f;
#pragma unroll
            for (int i = 0; i < 4; ++i)
#pragma unroll
                for (int r = 0; r < 4; ++r)
                    O[(size_t)(orow + i * 16 + r) * N + ocol + j * 16] = acc[i][j][r] + bv;
        }
    }
}

// ------------------------------------------------------------- attention
// One block = (b, head-PAIR, 64-row q-tile), 512 threads = 8 waves.
// Waves 0-3 process head h0 (16 q rows each), waves 4-7 head h0+1 — the two
// GQA-sibling heads share each staged K/V tile (2x MFMA per staged byte) with
// no extra per-wave registers.
// __launch_bounds__(512,4): VGPR cap 128 — the R5/R7 spill lesson (cap 85 at
// 6 waves/EU forced ~50 VGPRs of state into scratch: WRITE_SIZE +44MB).
// LDS = K 16K + Vt 16K + P 16K = 48KB -> 2 blocks/CU (VGPR-bound).
__global__ __launch_bounds__(512, 4)
void k_attn(const unsigned short* __restrict__ qkv,  // [B,T,3072] bf16
            const unsigned short* __restrict__ vtb,  // [B,HKV,D,T] bf16
            unsigned short* __restrict__ yb) {       // [B,T,C] bf16
    const int T = 2048, C = 2048, QKVC = 3072;
    const int qt = (int)gridDim.x - 1 - (int)blockIdx.x;   // long blocks first
    const int hk = blockIdx.y >> 1;
    const int h  = hk * 4 + (blockIdx.y & 1) * 2 + (threadIdx.x >> 8);  // wave 0-3: h0, 4-7: h0+1
    const int b  = blockIdx.z;

    const int t = threadIdx.x, lane = t & 63, wave = t >> 6;   // 0..7
    const int wv = wave & 3;                                   // q-row group in tile
    const int r16 = lane & 15, quad = lane >> 4;

    __shared__ unsigned short ldsK[4 * 64 * 32];     // [kk][s][32d]
    __shared__ unsigned short ldsVt[2 * 128 * 32];   // [kk][d][32s]
    __shared__ unsigned short ldsP[8][16 * 64];      // per-wave, s XOR-swizzled

    const int qBase = qt * 64;
    const int swz = (r16 & 7) * 8;

    // Q B-fragments (this wave's head), reused every kv tile
    const size_t qrow = (size_t)b * T + qBase + wv * 16 + r16;
    bf16x8 qf[4];
#pragma unroll
    for (int kk = 0; kk < 4; ++kk)
        qf[kk] = *(const bf16x8*)(qkv + qrow * QKVC + h * 128 + kk * 32 + quad * 8);

    f32x4 o[8];
#pragma unroll
    for (int dj = 0; dj < 8; ++dj) { f32x4 z = {0.f, 0.f, 0.f, 0.f}; o[dj] = z; }
    float lpart = 0.f;

    const float sc_l2e = 0.08838834764831845f * 1.4426950408889634f; // scale*log2(e)
    const float MSUB   = 10.0f * 1.4426950408889634f;                // fixed max (log2)

    const unsigned short* kg = qkv + (size_t)b * T * QKVC + 2048 + hk * 128;
    const unsigned short* vt = vtb + (size_t)(b * 4 + hk) * 128 * T;

    const int lr = lane >> 2;          // 0..15
    const int lc = (lane & 3) * 8;     // 0,8,16,24
    unsigned short* Pw = &ldsP[wave][0];
    const int qloc = wv * 16 + r16;

    for (int kv = 0; kv <= qBase; kv += 64) {
        // ---- async stage across all 8 waves: 16 K-chunks + 16 Vt-chunks of 1KB
#pragma unroll
        for (int q = 0; q < 2; ++q) {
            int c = wave * 2 + q;
            int kk = c >> 2, s16 = c & 3;
            gll16(kg + (size_t)(kv + s16 * 16 + lr) * QKVC + kk * 32 + lc,
                  ldsK + kk * 2048 + s16 * 512);
            int kk2 = c >> 3, d16 = c & 7;
            gll16(vt + (size_t)(d16 * 16 + lr) * T + kv + kk2 * 32 + lc,
                  ldsVt + kk2 * 4096 + d16 * 512);
        }
        asm volatile("s_waitcnt vmcnt(0)" ::: "memory");
        __syncthreads();

        // ---- S^T = K Q^T : C-layout q = r16, kv_local = mi*16 + quad*4 + reg
        f32x4 sacc[4];
#pragma unroll
        for (int mi = 0; mi < 4; ++mi) { f32x4 z = {0.f, 0.f, 0.f, 0.f}; sacc[mi] = z; }
#pragma unroll
        for (int mi = 0; mi < 4; ++mi)
#pragma unroll
            for (int kk = 0; kk < 4; ++kk) {
                bf16x8 kf = *(const bf16x8*)(ldsK + kk * 2048 + (mi * 16 + r16) * 32 + quad * 8);
                sacc[mi] = mfma16(kf, qf[kk], sacc[mi]);
            }

        // ---- p = e^{s*scale - 10}, causal mask on diag, packed b64 P write
        const bool diag = (kv == qBase);
#pragma unroll
        for (int mi = 0; mi < 4; ++mi) {
            float pv[4];
#pragma unroll
            for (int i = 0; i < 4; ++i) {
                float p = exp2f(sacc[mi][i] * sc_l2e - MSUB);
                if (diag && (mi * 16 + quad * 4 + i > qloc)) p = 0.f;
                lpart += p;
                pv[i] = p;
            }
            union { ushort4 u4; __bf16 hh[4]; } pk;
            pk.hh[0] = (__bf16)pv[0]; pk.hh[1] = (__bf16)pv[1];
            pk.hh[2] = (__bf16)pv[2]; pk.hh[3] = (__bf16)pv[3];
            *(ushort4*)(Pw + r16 * 64 + ((mi * 16 + quad * 4) ^ swz)) = pk.u4;
        }
        asm volatile("s_waitcnt lgkmcnt(0)" ::: "memory");

        // ---- O += P V  (A=P from swizzled LDS, B=V^T frags)
#pragma unroll
        for (int kk = 0; kk < 2; ++kk) {
            bf16x8 pf = *(const bf16x8*)(Pw + r16 * 64 + ((kk * 32 + quad * 8) ^ swz));
#pragma unroll
            for (int dj = 0; dj < 8; ++dj) {
                bf16x8 vf = *(const bf16x8*)(ldsVt + kk * 4096 + (dj * 16 + r16) * 32 + quad * 8);
                o[dj] = mfma16(pf, vf, o[dj]);
            }
        }
        __syncthreads();
    }

    // ---- final row-sum reduce (q = r16 replicated over quads) + gather + store
    lpart += __shfl_xor(lpart, 16, 64);
    lpart += __shfl_xor(lpart, 32, 64);
#pragma unroll
    for (int i = 0; i < 4; ++i) {
        float inv = 1.0f / __shfl(lpart, quad * 4 + i, 64);
        size_t row = (size_t)b * T + qBase + wv * 16 + quad * 4 + i;
#pragma unroll
        for (int dj = 0; dj < 8; ++dj)
            yb[row * C + h * 128 + dj * 16 + r16] = f2bf(o[dj][i] * inv);
    }
}

// ------------------------------------------------------------------ launch
extern "C" void kernel_launch(void* const* d_in, const int* in_sizes, int n_in,
                              void* d_out, int out_size, void* d_ws, size_t ws_size,
                              hipStream_t stream) {
    (void)in_sizes; (void)n_in; (void)out_size; (void)ws_size;
    const float* x   = (const float*)d_in[0];
    const float* Wq  = (const float*)d_in[1];
    const float* Wkv = (const float*)d_in[2];
    const float* Wc  = (const float*)d_in[3];
    const float* bc  = (const float*)d_in[4];

    const int B = 4, T = 2048, C = 2048;
    const int M = B * T;          // 8192
    const int NKV = 1024;         // 2*HKV*D
    const int NQKV = C + NKV;     // 3072

    char* ws = (char*)d_ws;
    unsigned short* xb    = (unsigned short*)ws; ws += (size_t)M * C * 2;
    unsigned short* WqkvT = (unsigned short*)ws; ws += (size_t)NQKV * C * 2;
    unsigned short* WcT   = (unsigned short*)ws; ws += (size_t)C * C * 2;
    unsigned short* qkv   = (unsigned short*)ws; ws += (size_t)M * NQKV * 2;
    unsigned short* ybuf  = (unsigned short*)ws; ws += (size_t)M * C * 2;
    unsigned short* vtb   = (unsigned short*)ws; ws += (size_t)B * 4 * 128 * T * 2;

    const int nX = M * C;
    k_f32_to_bf16<<<nX / 4 / 256, 256, 0, stream>>>(x, xb, nX);
    // WqkvT[n][k]: rows 0..2047 = Wq^T, rows 2048..3071 = Wkv^T
    k_transpose_bf16<<<dim3(C / 64, C / 64), 256, 0, stream>>>(Wq, WqkvT, C, C);
    k_transpose_bf16<<<dim3(NKV / 64, C / 64), 256, 0, stream>>>(Wkv, WqkvT + (size_t)C * C, C, NKV);
    k_transpose_bf16<<<dim3(C / 64, C / 64), 256, 0, stream>>>(Wc, WcT, C, C);

    // fused q/k/v projection: qkv[M][3072]
    k_gemm_bt<true><<<dim3(NQKV / 128, M / 128), 256, 0, stream>>>(xb, WqkvT, qkv, nullptr, M, NQKV, C);

    k_transpose_v<<<dim3(T / 64, 2, B * 4), 256, 0, stream>>>(qkv, vtb);

    k_attn<<<dim3(T / 64, 8, B), 512, 0, stream>>>(qkv, vtb, ybuf);

    k_gemm_bt<false><<<dim3(C / 128, M / 128), 256, 0, stream>>>(ybuf, WcT, (void*)d_out, bc, M, C, C);
}